// Round 3
// baseline (74.457 us; speedup 1.0000x reference)
//
#include <hip/hip_runtime.h>
#include <stdint.h>

// JointGNNEncoder fused 2-layer GCN, MI355X (gfx950).
// out[b] = mean_n ReLU( A @ ( ReLU( A @ (X W1) + b1 ) W2 ) + b2 )
// Using A@(X W)=(A@X) W, A is tridiagonal (chains are index-contiguous).
// prep kernel: W1^T / W2^T -> bf16, pre-swizzled images in d_ws.
// main kernel: 8 graphs (192 rows) per 512-thread block, fully fused.
// R3 fix: ldsA load covered all 576 elems (was `if (tid<576)` with 512 threads
// -> rows 21-23 of A_norm uninitialized -> absmax 8.8e-2 in R1/R2).

typedef __attribute__((ext_vector_type(8))) __bf16 bf16x8;
typedef __attribute__((ext_vector_type(4))) float f32x4;

#define GLP(p) ((const __attribute__((address_space(1))) void*)(p))
#define LDP(p) ((__attribute__((address_space(3))) void*)(p))
// byteoff includes row*stride; XOR bits 4..6 spread 16B slots across banks
#define SWZ(row, byteoff) ((unsigned)(byteoff) ^ ((((unsigned)(row)) & 7u) << 4))

__device__ __forceinline__ unsigned short f2bf(float f) {
  unsigned int u = __builtin_bit_cast(unsigned int, f);
  u += 0x7fffu + ((u >> 16) & 1u);   // round to nearest even
  return (unsigned short)(u >> 16);
}
__device__ __forceinline__ float bf2f(unsigned short s) {
  unsigned int u = ((unsigned int)s) << 16;
  return __builtin_bit_cast(float, u);
}

// ---------------------------------------------------------------------------
// prep: build swizzled bf16 W1^T (256x64) and W2^T (256x256, four 256x64
// chunks) images in ws. W1 global is (64,256) [k][h]; W2 is (256,256) [f][o].
// ws layout: [0,32768): W1T; [32768, 163840): 4 chunks of 32768 B.
// element (row,kc) of a 256x64 image lives at byte (row*128+kc*2)^((row&7)<<4)
// ---------------------------------------------------------------------------
__global__ void prep_kernel(const float* __restrict__ W1,
                            const float* __restrict__ W2,
                            unsigned char* __restrict__ ws) {
  int t = blockIdx.x * blockDim.x + threadIdx.x;
  union { unsigned short s[8]; uint4 v; } tmp;
  if (t < 2048) {                       // W1T: 256 h * 8 kgroups
    int h = t >> 3, k0 = (t & 7) * 8;
#pragma unroll
    for (int j = 0; j < 8; ++j) tmp.s[j] = f2bf(W1[(k0 + j) * 256 + h]);
    unsigned byte = SWZ(h, h * 128 + k0 * 2);
    *(uint4*)(ws + byte) = tmp.v;
  } else if (t < 10240) {               // W2T: 256 o * 32 fgroups
    int q = t - 2048;
    int o = q >> 5, f0 = (q & 31) * 8;
    int c = f0 >> 6, fc = f0 & 63;
#pragma unroll
    for (int j = 0; j < 8; ++j) tmp.s[j] = f2bf(W2[(f0 + j) * 256 + o]);
    unsigned byte = 32768u + (unsigned)c * 32768u + SWZ(o, o * 128 + fc * 2);
    *(uint4*)(ws + byte) = tmp.v;
  }
}

// ---------------------------------------------------------------------------
// main fused kernel: 512 threads = 8 waves; block = 8 graphs = 192 rows.
// wave grid: 4 o-waves (tile 64 = 4 frags) x 2 m-waves (tile 96 = 6 frags).
// ---------------------------------------------------------------------------
__launch_bounds__(512, 2)
__global__ void gnn_kernel(const float* __restrict__ X,
                           const float* __restrict__ b1g,
                           const float* __restrict__ b2g,
                           const float* __restrict__ Ag,
                           const unsigned char* __restrict__ ws,
                           float* __restrict__ out) {
  __shared__ __align__(16) unsigned char ldsW[32768];   // W1T, then W2T chunks
  __shared__ __align__(16) unsigned char ldsX[24576];   // X' 192x64 bf16 swz
  __shared__ __align__(16) unsigned char ldsH[98304];   // H1 192x256 bf16 swz; reused for Z
  __shared__ __align__(16) float ldsA[576];
  __shared__ __align__(16) float ldsB1[256];
  __shared__ __align__(16) float ldsB2[256];

  const int tid  = threadIdx.x;
  const int lane = tid & 63;
  const int wid  = tid >> 6;
  const int g0   = blockIdx.x * 8;
  const long row0 = (long)g0 * 24;

  // ---- stage W1T (async, drained by the next __syncthreads)
  {
    int base = wid * 4096;
#pragma unroll
    for (int it = 0; it < 4; ++it) {
      int off = base + it * 1024;
      __builtin_amdgcn_global_load_lds(GLP(ws + off + lane * 16),
                                       LDP(ldsW + off), 16, 0, 0);
    }
  }
  // 576 > blockDim: strided loop (R1/R2 bug was `if (tid < 576)`)
  for (int i = tid; i < 576; i += 512) ldsA[i] = Ag[i];
  if (tid < 256) { ldsB1[tid] = b1g[tid]; ldsB2[tid] = b2g[tid]; }
  __syncthreads();

  // ---- X' = (A @ X) rows, tridiagonal mix, cast bf16, swizzled into ldsX
#pragma unroll
  for (int it = 0; it < 6; ++it) {
    int idx = tid + it * 512;            // 192 rows x 16 float4-chunks
    int m   = idx >> 4;
    int c4  = (idx & 15) * 4;
    int n   = m - (m / 24) * 24;
    const float* xr = X + (row0 + m) * 64 + c4;
    float wmid = ldsA[n * 24 + n];
    float wdn  = (n > 0)  ? ldsA[n * 24 + n - 1] : 0.f;
    float wup  = (n < 23) ? ldsA[n * 24 + n + 1] : 0.f;
    float4 xc = *(const float4*)xr;
    float ax = wmid * xc.x, ay = wmid * xc.y, az = wmid * xc.z, aw = wmid * xc.w;
    if (wdn != 0.f) {
      float4 xd = *(const float4*)(xr - 64);
      ax += wdn * xd.x; ay += wdn * xd.y; az += wdn * xd.z; aw += wdn * xd.w;
    }
    if (wup != 0.f) {
      float4 xu = *(const float4*)(xr + 64);
      ax += wup * xu.x; ay += wup * xu.y; az += wup * xu.z; aw += wup * xu.w;
    }
    ushort4 p; p.x = f2bf(ax); p.y = f2bf(ay); p.z = f2bf(az); p.w = f2bf(aw);
    *(ushort4*)(ldsX + SWZ(m, m * 128 + c4 * 2)) = p;
  }
  __syncthreads();

  const int ow   = wid & 3;              // o/h wave: tile base ow*64
  const int mw   = wid >> 2;             // m wave: tile base mw*96
  const int r16  = lane & 15;
  const int kgrp = (lane >> 4) * 8;      // k element offset within 32

  f32x4 acc[4][6];
  const f32x4 z4 = {0.f, 0.f, 0.f, 0.f};
#pragma unroll
  for (int i = 0; i < 4; ++i)
#pragma unroll
    for (int j = 0; j < 6; ++j) acc[i][j] = z4;

  // ---- GEMM1: D[h][m] = W1T(h,k) * X'(m,k)^T, K=64
#pragma unroll
  for (int ks = 0; ks < 2; ++ks) {
    bf16x8 af[4], bf[6];
    int koff = (ks * 32 + kgrp) * 2;
#pragma unroll
    for (int fi = 0; fi < 4; ++fi) {
      int h = ow * 64 + fi * 16 + r16;
      af[fi] = *(const bf16x8*)(ldsW + SWZ(h, h * 128 + koff));
    }
#pragma unroll
    for (int fj = 0; fj < 6; ++fj) {
      int m = mw * 96 + fj * 16 + r16;
      bf[fj] = *(const bf16x8*)(ldsX + SWZ(m, m * 128 + koff));
    }
#pragma unroll
    for (int fi = 0; fi < 4; ++fi)
#pragma unroll
      for (int fj = 0; fj < 6; ++fj)
        acc[fi][fj] = __builtin_amdgcn_mfma_f32_16x16x32_bf16(af[fi], bf[fj], acc[fi][fj], 0, 0, 0);
  }

  // ---- epilogue1: bias + ReLU, write H1[m][h] bf16 (4 consecutive h = 8B)
  {
    int hr = (lane >> 4) * 4;
#pragma unroll
    for (int fi = 0; fi < 4; ++fi) {
      int h = ow * 64 + fi * 16 + hr;
      float4 bb = *(const float4*)&ldsB1[h];
#pragma unroll
      for (int fj = 0; fj < 6; ++fj) {
        int m = mw * 96 + fj * 16 + r16;
        f32x4 v = acc[fi][fj];
        ushort4 p;
        p.x = f2bf(fmaxf(v[0] + bb.x, 0.f));
        p.y = f2bf(fmaxf(v[1] + bb.y, 0.f));
        p.z = f2bf(fmaxf(v[2] + bb.z, 0.f));
        p.w = f2bf(fmaxf(v[3] + bb.w, 0.f));
        *(ushort4*)(ldsH + SWZ(m, m * 512 + h * 2)) = p;
      }
    }
  }
  __syncthreads();

  // ---- GEMM2: D[o][m] = W2T(o,f) * H1(m,f)^T, K=256 in 4 chunks of 64
#pragma unroll
  for (int i = 0; i < 4; ++i)
#pragma unroll
    for (int j = 0; j < 6; ++j) acc[i][j] = z4;

  for (int c = 0; c < 4; ++c) {
    {
      int base = wid * 4096;
#pragma unroll
      for (int it = 0; it < 4; ++it) {
        int off = base + it * 1024;
        __builtin_amdgcn_global_load_lds(GLP(ws + 32768 + c * 32768 + off + lane * 16),
                                         LDP(ldsW + off), 16, 0, 0);
      }
    }
    __syncthreads();   // drains vmcnt: chunk visible
#pragma unroll
    for (int ks = 0; ks < 2; ++ks) {
      bf16x8 af[4], bf[6];
      int koff = (ks * 32 + kgrp) * 2;                // within 64-wide chunk row
      int foff = (c * 64 + ks * 32 + kgrp) * 2;       // within 256-wide H row
#pragma unroll
      for (int fi = 0; fi < 4; ++fi) {
        int o = ow * 64 + fi * 16 + r16;
        af[fi] = *(const bf16x8*)(ldsW + SWZ(o, o * 128 + koff));
      }
#pragma unroll
      for (int fj = 0; fj < 6; ++fj) {
        int m = mw * 96 + fj * 16 + r16;
        bf[fj] = *(const bf16x8*)(ldsH + SWZ(m, m * 512 + foff));
      }
#pragma unroll
      for (int fi = 0; fi < 4; ++fi)
#pragma unroll
        for (int fj = 0; fj < 6; ++fj)
          acc[fi][fj] = __builtin_amdgcn_mfma_f32_16x16x32_bf16(af[fi], bf[fj], acc[fi][fj], 0, 0, 0);
    }
    __syncthreads();   // protect ldsW before next chunk / ldsH before Z dump
  }

  // ---- dump Z (no bias/relu yet) into ldsH as bf16 [m][o]
  {
    int orr = (lane >> 4) * 4;
#pragma unroll
    for (int fi = 0; fi < 4; ++fi) {
      int o = ow * 64 + fi * 16 + orr;
#pragma unroll
      for (int fj = 0; fj < 6; ++fj) {
        int m = mw * 96 + fj * 16 + r16;
        f32x4 v = acc[fi][fj];
        ushort4 p;
        p.x = f2bf(v[0]); p.y = f2bf(v[1]); p.z = f2bf(v[2]); p.w = f2bf(v[3]);
        *(ushort4*)(ldsH + SWZ(m, m * 512 + o * 2)) = p;
      }
    }
  }
  __syncthreads();

  // ---- final: out[g][o] = 1/24 * sum_n ReLU( tri-mix(Z)[n][o] + b2[o] )
  {
    const int g  = tid >> 6;             // one graph per wave
    const int o4 = (lane) * 4;
    const int rb = g * 24;
    float4 bt = *(const float4*)&ldsB2[o4];
    float bb[4] = {bt.x, bt.y, bt.z, bt.w};
    float s[4]  = {0.f, 0.f, 0.f, 0.f};
    float zp[4] = {0.f, 0.f, 0.f, 0.f};
    float zc[4], zn[4];
    {
      ushort4 z = *(const ushort4*)(ldsH + SWZ(rb, rb * 512 + o4 * 2));
      zc[0] = bf2f(z.x); zc[1] = bf2f(z.y); zc[2] = bf2f(z.z); zc[3] = bf2f(z.w);
      int r = rb + 1;
      ushort4 y = *(const ushort4*)(ldsH + SWZ(r, r * 512 + o4 * 2));
      zn[0] = bf2f(y.x); zn[1] = bf2f(y.y); zn[2] = bf2f(y.z); zn[3] = bf2f(y.w);
    }
#pragma unroll
    for (int nn = 0; nn < 24; ++nn) {
      const float w0 = ldsA[nn * 24 + nn];
      float q[4];
#pragma unroll
      for (int j = 0; j < 4; ++j) q[j] = w0 * zc[j] + bb[j];
      if (nn > 0) {
        const float wd = ldsA[nn * 24 + nn - 1];
#pragma unroll
        for (int j = 0; j < 4; ++j) q[j] += wd * zp[j];
      }
      if (nn < 23) {
        const float wu = ldsA[nn * 24 + nn + 1];
#pragma unroll
        for (int j = 0; j < 4; ++j) q[j] += wu * zn[j];
      }
#pragma unroll
      for (int j = 0; j < 4; ++j) s[j] += fmaxf(q[j], 0.f);
#pragma unroll
      for (int j = 0; j < 4; ++j) { zp[j] = zc[j]; zc[j] = zn[j]; }
      if (nn < 22) {
        int r = rb + nn + 2;
        ushort4 z = *(const ushort4*)(ldsH + SWZ(r, r * 512 + o4 * 2));
        zn[0] = bf2f(z.x); zn[1] = bf2f(z.y); zn[2] = bf2f(z.z); zn[3] = bf2f(z.w);
      }
    }
    float4 r4;
    r4.x = s[0] * (1.f / 24.f);
    r4.y = s[1] * (1.f / 24.f);
    r4.z = s[2] * (1.f / 24.f);
    r4.w = s[3] * (1.f / 24.f);
    *(float4*)(out + (size_t)(g0 + g) * 256 + o4) = r4;
  }
}

extern "C" void kernel_launch(void* const* d_in, const int* in_sizes, int n_in,
                              void* d_out, int out_size, void* d_ws, size_t ws_size,
                              hipStream_t stream) {
  (void)n_in; (void)out_size; (void)ws_size;
  const float* X  = (const float*)d_in[0];
  const float* W1 = (const float*)d_in[1];
  const float* b1 = (const float*)d_in[2];
  const float* W2 = (const float*)d_in[3];
  const float* b2 = (const float*)d_in[4];
  const float* A  = (const float*)d_in[5];
  float* out = (float*)d_out;
  unsigned char* ws = (unsigned char*)d_ws;

  int B = in_sizes[0] / (24 * 64);   // 8192
  prep_kernel<<<40, 256, 0, stream>>>(W1, W2, ws);
  gnn_kernel<<<B / 8, 512, 0, stream>>>(X, b1, b2, A, ws, out);
}

// Round 4
// 67.169 us; speedup vs baseline: 1.1085x; 1.1085x over previous
//
#include <hip/hip_runtime.h>
#include <stdint.h>

// JointGNNEncoder fused 2-layer GCN, MI355X (gfx950).
// out[b] = mean_n ReLU( A @ ( ReLU( A @ (X W1) + b1 ) W2 ) + b2 )
// A@(X W) = (A@X) W ; A is tridiagonal (chains are index-contiguous).
// R4: 4 graphs / 256-thread block (66 KB LDS -> 2 blocks/CU), weights packed
// in per-fragment lane order in ws and read direct from global (no ldsW, no
// staging barriers in GEMM2), native (__bf16) casts for packed cvt.

typedef __attribute__((ext_vector_type(8))) __bf16 bf16x8;
typedef __attribute__((ext_vector_type(4))) __bf16 bf16x4;
typedef __attribute__((ext_vector_type(4))) float f32x4;

// XOR bits 4..6 by row&7: spreads 16B slots of same-bank rows across banks
#define SWZ(row, byteoff) ((unsigned)(byteoff) ^ ((((unsigned)(row)) & 7u) << 4))

// ---------------------------------------------------------------------------
// prep: pack bf16 weights in per-fragment lane order.
// GEMM1 frag block idx = (hf*2 + ks), hf = ow*4+fi (0..15), ks (0..1):
//   lane l holds W1T(h = hf*16 + (l&15), k = ks*32 + (l>>4)*8 + j), j=0..7
//   -> 1 KB per block, 32 KB total at ws[0].
// GEMM2 frag block idx = ((of*4 + c)*2 + ks), of = ow*4+fi, c chunk (0..3):
//   lane l holds W2T(o = of*16 + (l&15), f = c*64 + ks*32 + (l>>4)*8 + j)
//   -> 128 KB at ws[32768]. Total 163840 B.
// ---------------------------------------------------------------------------
__global__ void prep_kernel(const float* __restrict__ W1,
                            const float* __restrict__ W2,
                            unsigned char* __restrict__ ws) {
  int t = blockIdx.x * blockDim.x + threadIdx.x;
  bf16x8 v;
  if (t < 2048) {                     // GEMM1: 32 blocks * 64 lanes
    int blk = t >> 6, l = t & 63;
    int ks = blk & 1, hf = blk >> 1;
    int h  = hf * 16 + (l & 15);
    int k0 = ks * 32 + (l >> 4) * 8;
#pragma unroll
    for (int j = 0; j < 8; ++j) v[j] = (__bf16)W1[(k0 + j) * 256 + h];
    *(bf16x8*)(ws + t * 16) = v;
  } else if (t < 10240) {             // GEMM2: 128 blocks * 64 lanes
    int t2 = t - 2048;
    int blk = t2 >> 6, l = t2 & 63;
    int ks = blk & 1;
    int c  = (blk >> 1) & 3;
    int of = blk >> 3;
    int o  = of * 16 + (l & 15);
    int f0 = c * 64 + ks * 32 + (l >> 4) * 8;
#pragma unroll
    for (int j = 0; j < 8; ++j) v[j] = (__bf16)W2[(f0 + j) * 256 + o];
    *(bf16x8*)(ws + 32768 + t2 * 16) = v;
  }
}

// ---------------------------------------------------------------------------
// main fused kernel: 256 threads = 4 waves; block = 4 graphs = 96 rows.
// wave wid owns o-tile wid*64 (4 frags fi); m-tile = all 96 rows (6 frags fj).
// ---------------------------------------------------------------------------
__launch_bounds__(256, 2)
__global__ void gnn_kernel(const float* __restrict__ X,
                           const float* __restrict__ b1g,
                           const float* __restrict__ b2g,
                           const float* __restrict__ Ag,
                           const unsigned char* __restrict__ ws,
                           float* __restrict__ out) {
  __shared__ __align__(16) unsigned char ldsX[96 * 128];   // X' bf16 swz  12.3K
  __shared__ __align__(16) unsigned char ldsH[96 * 512];   // H1/Z bf16 swz 49.2K
  __shared__ __align__(16) float ldsA[576];
  __shared__ __align__(16) float ldsB1[256];
  __shared__ __align__(16) float ldsB2[256];

  const int tid  = threadIdx.x;
  const int lane = tid & 63;
  const int wid  = tid >> 6;
  const int g0   = blockIdx.x * 4;
  const long row0 = (long)g0 * 24;

  for (int i = tid; i < 576; i += 256) ldsA[i] = Ag[i];
  ldsB1[tid] = b1g[tid];
  ldsB2[tid] = b2g[tid];
  __syncthreads();

  // ---- X' = (A @ X) rows (tridiagonal mix) -> bf16 swizzled into ldsX
#pragma unroll
  for (int it = 0; it < 6; ++it) {
    int idx = tid + it * 256;            // 96 rows x 16 float4-chunks
    int m   = idx >> 4;
    int c4  = (idx & 15) * 4;
    int n   = m - (m / 24) * 24;
    const float* xr = X + (row0 + m) * 64 + c4;
    float wmid = ldsA[n * 24 + n];
    float wdn  = (n > 0)  ? ldsA[n * 24 + n - 1] : 0.f;
    float wup  = (n < 23) ? ldsA[n * 24 + n + 1] : 0.f;
    float4 xc = *(const float4*)xr;
    float ax = wmid * xc.x, ay = wmid * xc.y, az = wmid * xc.z, aw = wmid * xc.w;
    if (wdn != 0.f) {
      float4 xd = *(const float4*)(xr - 64);
      ax += wdn * xd.x; ay += wdn * xd.y; az += wdn * xd.z; aw += wdn * xd.w;
    }
    if (wup != 0.f) {
      float4 xu = *(const float4*)(xr + 64);
      ax += wup * xu.x; ay += wup * xu.y; az += wup * xu.z; aw += wup * xu.w;
    }
    bf16x4 p;
    p[0] = (__bf16)ax; p[1] = (__bf16)ay; p[2] = (__bf16)az; p[3] = (__bf16)aw;
    *(bf16x4*)(ldsX + SWZ(m, m * 128 + c4 * 2)) = p;
  }
  __syncthreads();

  const int r16   = lane & 15;
  const int kgrp  = (lane >> 4) * 8;
  const int lbyte = lane * 16;

  f32x4 acc[4][6];
  const f32x4 z4 = {0.f, 0.f, 0.f, 0.f};
#pragma unroll
  for (int i = 0; i < 4; ++i)
#pragma unroll
    for (int j = 0; j < 6; ++j) acc[i][j] = z4;

  // ---- GEMM1: D[h][m] = W1T(h,k) * X'(m,k)^T, K=64; af from global (packed)
#pragma unroll
  for (int ks = 0; ks < 2; ++ks) {
    bf16x8 af[4], bf[6];
    int koff = (ks * 32 + kgrp) * 2;
#pragma unroll
    for (int fi = 0; fi < 4; ++fi)
      af[fi] = *(const bf16x8*)(ws + ((((wid * 4 + fi) * 2) + ks) << 10) + lbyte);
#pragma unroll
    for (int fj = 0; fj < 6; ++fj) {
      int m = fj * 16 + r16;
      bf[fj] = *(const bf16x8*)(ldsX + SWZ(m, m * 128 + koff));
    }
#pragma unroll
    for (int fi = 0; fi < 4; ++fi)
#pragma unroll
      for (int fj = 0; fj < 6; ++fj)
        acc[fi][fj] = __builtin_amdgcn_mfma_f32_16x16x32_bf16(af[fi], bf[fj], acc[fi][fj], 0, 0, 0);
  }

  // ---- epilogue1: bias + ReLU -> H1[m][h] bf16 (D: col=lane&15=m, row=(lane>>4)*4+reg=h)
  {
    int hr = (lane >> 4) * 4;
#pragma unroll
    for (int fi = 0; fi < 4; ++fi) {
      int h = wid * 64 + fi * 16 + hr;
      float4 bb = *(const float4*)&ldsB1[h];
#pragma unroll
      for (int fj = 0; fj < 6; ++fj) {
        int m = fj * 16 + r16;
        f32x4 v = acc[fi][fj];
        bf16x4 p;
        p[0] = (__bf16)fmaxf(v[0] + bb.x, 0.f);
        p[1] = (__bf16)fmaxf(v[1] + bb.y, 0.f);
        p[2] = (__bf16)fmaxf(v[2] + bb.z, 0.f);
        p[3] = (__bf16)fmaxf(v[3] + bb.w, 0.f);
        *(bf16x4*)(ldsH + SWZ(m, m * 512 + h * 2)) = p;
      }
    }
  }
  __syncthreads();

  // ---- GEMM2: D[o][m] = W2T(o,f) * H1(m,f)^T, K=256; af from global (packed)
#pragma unroll
  for (int i = 0; i < 4; ++i)
#pragma unroll
    for (int j = 0; j < 6; ++j) acc[i][j] = z4;

  const unsigned char* w2p = ws + 32768;
#pragma unroll
  for (int c = 0; c < 4; ++c) {
#pragma unroll
    for (int ks = 0; ks < 2; ++ks) {
      bf16x8 af[4], bf[6];
      int foff = (c * 64 + ks * 32 + kgrp) * 2;
#pragma unroll
      for (int fi = 0; fi < 4; ++fi)
        af[fi] = *(const bf16x8*)(w2p + (((((wid * 4 + fi) * 4) + c) * 2 + ks) << 10) + lbyte);
#pragma unroll
      for (int fj = 0; fj < 6; ++fj) {
        int m = fj * 16 + r16;
        bf[fj] = *(const bf16x8*)(ldsH + SWZ(m, m * 512 + foff));
      }
#pragma unroll
      for (int fi = 0; fi < 4; ++fi)
#pragma unroll
        for (int fj = 0; fj < 6; ++fj)
          acc[fi][fj] = __builtin_amdgcn_mfma_f32_16x16x32_bf16(af[fi], bf[fj], acc[fi][fj], 0, 0, 0);
    }
  }
  __syncthreads();   // all H1 reads done before Z overwrites ldsH

  // ---- dump Z (pre-bias/ReLU) into ldsH as bf16 [m][o]
  {
    int orr = (lane >> 4) * 4;
#pragma unroll
    for (int fi = 0; fi < 4; ++fi) {
      int o = wid * 64 + fi * 16 + orr;
#pragma unroll
      for (int fj = 0; fj < 6; ++fj) {
        int m = fj * 16 + r16;
        f32x4 v = acc[fi][fj];
        bf16x4 p;
        p[0] = (__bf16)v[0]; p[1] = (__bf16)v[1];
        p[2] = (__bf16)v[2]; p[3] = (__bf16)v[3];
        *(bf16x4*)(ldsH + SWZ(m, m * 512 + o * 2)) = p;
      }
    }
  }
  __syncthreads();

  // ---- final: out[g][o] = 1/24 * sum_n ReLU( tri-mix(Z)[n][o] + b2[o] )
  {
    const int g  = wid;                  // one graph per wave
    const int o4 = lane * 4;
    const int rb = g * 24;
    float4 bt = *(const float4*)&ldsB2[o4];
    float bb[4] = {bt.x, bt.y, bt.z, bt.w};
    float s[4]  = {0.f, 0.f, 0.f, 0.f};
    float zp[4] = {0.f, 0.f, 0.f, 0.f};
    float zc[4], zn[4];
    {
      bf16x4 z = *(const bf16x4*)(ldsH + SWZ(rb, rb * 512 + o4 * 2));
      bf16x4 y = *(const bf16x4*)(ldsH + SWZ(rb + 1, (rb + 1) * 512 + o4 * 2));
#pragma unroll
      for (int j = 0; j < 4; ++j) { zc[j] = (float)z[j]; zn[j] = (float)y[j]; }
    }
#pragma unroll
    for (int nn = 0; nn < 24; ++nn) {
      const float w0 = ldsA[nn * 24 + nn];
      float q[4];
#pragma unroll
      for (int j = 0; j < 4; ++j) q[j] = w0 * zc[j] + bb[j];
      if (nn > 0) {
        const float wd = ldsA[nn * 24 + nn - 1];
#pragma unroll
        for (int j = 0; j < 4; ++j) q[j] += wd * zp[j];
      }
      if (nn < 23) {
        const float wu = ldsA[nn * 24 + nn + 1];
#pragma unroll
        for (int j = 0; j < 4; ++j) q[j] += wu * zn[j];
      }
#pragma unroll
      for (int j = 0; j < 4; ++j) s[j] += fmaxf(q[j], 0.f);
#pragma unroll
      for (int j = 0; j < 4; ++j) { zp[j] = zc[j]; zc[j] = zn[j]; }
      if (nn < 22) {
        int r = rb + nn + 2;
        bf16x4 z = *(const bf16x4*)(ldsH + SWZ(r, r * 512 + o4 * 2));
#pragma unroll
        for (int j = 0; j < 4; ++j) zn[j] = (float)z[j];
      }
    }
    float4 r4;
    r4.x = s[0] * (1.f / 24.f);
    r4.y = s[1] * (1.f / 24.f);
    r4.z = s[2] * (1.f / 24.f);
    r4.w = s[3] * (1.f / 24.f);
    *(float4*)(out + (size_t)(g0 + g) * 256 + o4) = r4;
  }
}

extern "C" void kernel_launch(void* const* d_in, const int* in_sizes, int n_in,
                              void* d_out, int out_size, void* d_ws, size_t ws_size,
                              hipStream_t stream) {
  (void)n_in; (void)out_size; (void)ws_size;
  const float* X  = (const float*)d_in[0];
  const float* W1 = (const float*)d_in[1];
  const float* b1 = (const float*)d_in[2];
  const float* W2 = (const float*)d_in[3];
  const float* b2 = (const float*)d_in[4];
  const float* A  = (const float*)d_in[5];
  float* out = (float*)d_out;
  unsigned char* ws = (unsigned char*)d_ws;

  int B = in_sizes[0] / (24 * 64);   // 8192
  prep_kernel<<<40, 256, 0, stream>>>(W1, W2, ws);
  gnn_kernel<<<B / 4, 256, 0, stream>>>(X, b1, b2, A, ws, out);
}